// Round 6
// baseline (169.156 us; speedup 1.0000x reference)
//
#include <hip/hip_runtime.h>

// Dtype contract: device buffers FP32 (reference dtypes); internal bf16 MFMA,
// fp32 accumulate. Tolerance is bf16-grade (2% of absmax).
// dur_us model: Σ(kernels) + ~65 us fixed harness resets (ws poison 41.6 us
// + input restore ~21 us) — only the kernel sum is controllable.

#define BATCH 8
#define SEQ   2048
#define CIN   1024
#define HDIM  64
#define NROW  (BATCH * SEQ)      // 16384
#define NQT   (NROW / 16)        // 1024 q-tiles
#define UNITS 576                // per batch: sum over qt of (qt/16+1)

typedef __attribute__((ext_vector_type(8))) short bf16x8;
typedef __attribute__((ext_vector_type(4))) short u16x4;
typedef __attribute__((ext_vector_type(4))) float f32x4;

__device__ __forceinline__ unsigned short f2bf(float f) {
  unsigned int u = __builtin_bit_cast(unsigned int, f);
  u += 0x7fffu + ((u >> 16) & 1u);          // RNE
  return (unsigned short)(u >> 16);
}
__device__ __forceinline__ float bf2f(unsigned short h) {
  return __builtin_bit_cast(float, (unsigned int)h << 16);
}
__device__ __forceinline__ u16x4 pack4(f32x4 a) {
  u16x4 r;
  r[0] = (short)f2bf(a[0]); r[1] = (short)f2bf(a[1]);
  r[2] = (short)f2bf(a[2]); r[3] = (short)f2bf(a[3]);
  return r;
}

// ---------------- Kernel 0: W [C][HD] fp32 -> Wt [HD][C] bf16 (LDS tiles) ---
__global__ __launch_bounds__(256) void wtrans_k(const float* __restrict__ wq,
                                                const float* __restrict__ wk,
                                                const float* __restrict__ wv,
                                                unsigned short* __restrict__ wt) {
  __shared__ unsigned short lds[64][65];
  const int m  = blockIdx.x >> 4;
  const int c0 = (blockIdx.x & 15) * 64;
  const float* w = (m == 0) ? wq : (m == 1) ? wk : wv;
  const int nl = threadIdx.x & 63, gr = threadIdx.x >> 6;
#pragma unroll
  for (int i = 0; i < 16; ++i) {
    int cl = gr * 16 + i;
    lds[cl][nl] = f2bf(w[(size_t)(c0 + cl) * HDIM + nl]);
  }
  __syncthreads();
#pragma unroll
  for (int i = 0; i < 16; ++i) {
    int n = gr * 16 + i;
    wt[(size_t)m * 65536 + n * CIN + c0 + nl] = lds[nl][n];
  }
}

// ---------------- Kernel 1: QKV projection, LDS-staged GEMM -----------------
// (unchanged; ~38 us)
__global__ __launch_bounds__(512) void qkv_proj_k(const float* __restrict__ x,
                                                  const unsigned short* __restrict__ wt,
                                                  unsigned short* __restrict__ q,
                                                  unsigned short* __restrict__ k,
                                                  unsigned short* __restrict__ vt) {
  __shared__ __align__(16) unsigned char ldsb[28672];   // x @0, wt @4096
  const int tid  = threadIdx.x;
  const int lane = tid & 63;
  const int w    = tid >> 6;
  const int lr   = lane & 15, lg = lane >> 4;
  const int wm   = w & 1, wn = w >> 1;
  const int row0 = blockIdx.x * 32;

  const int trow  = tid >> 4;
  const int tcol4 = (tid & 15) * 4;
  const float* xg = x + (size_t)(row0 + trow) * CIN + tcol4;
  const int xoff  = trow * 128 + (((tcol4 >> 3) ^ (trow & 7)) << 4) + ((tcol4 & 4) << 1);

  const int wrow_ = tid >> 3;
  const int wg8   = tid & 7;
  const unsigned short* wg[3];
  int woff[3];
#pragma unroll
  for (int c = 0; c < 3; ++c) {
    int wrow = c * 64 + wrow_;
    wg[c]   = wt + (size_t)wrow * CIN + wg8 * 8;
    woff[c] = 4096 + wrow * 128 + ((wg8 ^ (wrow & 7)) << 4);
  }

  f32x4 acc[3];
#pragma unroll
  for (int i = 0; i < 3; ++i) acc[i] = (f32x4){0.f, 0.f, 0.f, 0.f};

  const int arow_off = (wm * 16 + lr) * 128;
  const int brow0    = wn * 48 + lr;

#pragma unroll 1
  for (int t = 0; t < 16; ++t) {
    const int k0 = t * 64;
    f32x4 xv = *(const f32x4*)(xg + k0);
    bf16x8 w0 = *(const bf16x8*)(wg[0] + k0);
    bf16x8 w1 = *(const bf16x8*)(wg[1] + k0);
    bf16x8 w2 = *(const bf16x8*)(wg[2] + k0);
    __syncthreads();
    *(u16x4*)(void*)(ldsb + xoff)    = pack4(xv);
    *(bf16x8*)(void*)(ldsb + woff[0]) = w0;
    *(bf16x8*)(void*)(ldsb + woff[1]) = w1;
    *(bf16x8*)(void*)(ldsb + woff[2]) = w2;
    __syncthreads();
#pragma unroll
    for (int kk = 0; kk < 2; ++kk) {
      const int swz = (((kk << 2) | lg) ^ (lr & 7)) << 4;
      bf16x8 af = *(const bf16x8*)(void*)(ldsb + arow_off + swz);
#pragma unroll
      for (int f = 0; f < 3; ++f) {
        bf16x8 bf_ = *(const bf16x8*)(void*)(ldsb + 4096 + (brow0 + f * 16) * 128 + swz);
        acc[f] = __builtin_amdgcn_mfma_f32_16x16x32_bf16(af, bf_, acc[f], 0, 0, 0);
      }
    }
  }

#pragma unroll
  for (int f = 0; f < 3; ++f) {
    const int gc  = wn * 48 + f * 16;
    const int mat = gc >> 6;
    const int hd  = (gc & 63) + lr;
#pragma unroll
    for (int j = 0; j < 4; ++j) {
      int grow = row0 + wm * 16 + lg * 4 + j;
      float v = acc[f][j];
      if (mat == 0) {
        q[(size_t)grow * HDIM + hd] = f2bf(v * 0.03125f);   // fold 1/sqrt(C)
      } else if (mat == 1) {
        k[(size_t)grow * HDIM + hd] = f2bf(v);
      } else {
        int b = grow >> 11, tp = grow & 2047;
        vt[((size_t)b * HDIM + hd) * SEQ + tp] = f2bf(v);
      }
    }
  }
}

// ---------------- Kernel 2: causal flash attention, balanced split-KV -------
// Work unit = (b, qt, seg): q-tile qt has S(qt)=qt/16+1 segments, so EVERY
// wave processes 1-4 KV tiles of 64 keys (near-uniform -> no drain tail).
// 4 independent waves per 256-thr block, per-wave LDS slice, no block
// barriers; register-light body (TLP over ILP).
__global__ __launch_bounds__(256) void attn_k(const unsigned short* __restrict__ q,
                                              const unsigned short* __restrict__ k,
                                              const unsigned short* __restrict__ vt,
                                              float* __restrict__ opart,
                                              float* __restrict__ m_l) {
  __shared__ __align__(16) unsigned short plds[4][16][72];  // 144B row stride
  const int lane = threadIdx.x & 63;
  const int w    = threadIdx.x >> 6;
  const int lr = lane & 15, lg = lane >> 4;
  const int u    = blockIdx.x * 4 + w;      // 0 .. 8*UNITS-1
  const int b    = u / UNITS;
  const int unit = u - b * UNITS;
  // decode unit -> (a, qt, seg): block a covers units [8a(a+1), 8(a+1)(a+2))
  int a = 0;
#pragma unroll
  for (int i = 0; i < 7; ++i) if (8 * (a + 1) * (a + 2) <= unit) ++a;
  const int S    = a + 1;
  const int rem  = unit - 8 * a * S;
  const int qt   = 16 * a + rem / S;
  const int seg  = rem - (rem / S) * S;
  const int row0 = qt * 16;
  const int p    = b * UNITS + unit;        // partial slot
  unsigned short (*pw)[72] = plds[w];

  const unsigned short* qb_ = q  + (size_t)b * SEQ * HDIM;
  const unsigned short* kb_ = k  + (size_t)b * SEQ * HDIM;
  const unsigned short* vb_ = vt + (size_t)b * HDIM * SEQ;

  bf16x8 qf0 = *(const bf16x8*)(qb_ + (row0 + lr) * HDIM + lg * 8);
  bf16x8 qf1 = *(const bf16x8*)(qb_ + (row0 + lr) * HDIM + 32 + lg * 8);

  f32x4 o[4];
#pragma unroll
  for (int n = 0; n < 4; ++n) o[n] = (f32x4){0.f, 0.f, 0.f, 0.f};
  float m_run = -INFINITY, l_run = 0.f;
  const int   qrow = row0 + lr;
  const float LOG2E = 1.44269504f;
  const int nt = (qt >> 2) + 1;             // = ceil((row0+16)/64)
  const int lo = (nt * seg) / S;
  const int hi = (nt * (seg + 1)) / S;

  for (int t = lo; t < hi; ++t) {
    const int kv = t * 64;
    f32x4 sv[4];
#pragma unroll
    for (int f = 0; f < 4; ++f) {
      bf16x8 ka0 = *(const bf16x8*)(kb_ + (kv + f * 16 + lr) * HDIM + lg * 8);
      bf16x8 ka1 = *(const bf16x8*)(kb_ + (kv + f * 16 + lr) * HDIM + 32 + lg * 8);
      sv[f] = (f32x4){0.f, 0.f, 0.f, 0.f};
      sv[f] = __builtin_amdgcn_mfma_f32_16x16x32_bf16(ka0, qf0, sv[f], 0, 0, 0);
      sv[f] = __builtin_amdgcn_mfma_f32_16x16x32_bf16(ka1, qf1, sv[f], 0, 0, 0);
    }
    if (kv + 63 > row0) {                    // wave-uniform: tile touches diagonal
#pragma unroll
      for (int f = 0; f < 4; ++f)
#pragma unroll
        for (int j = 0; j < 4; ++j)
          if (kv + f * 16 + lg * 4 + j > qrow) sv[f][j] = -INFINITY;
    }
    float tm = -INFINITY;
#pragma unroll
    for (int f = 0; f < 4; ++f)
#pragma unroll
      for (int j = 0; j < 4; ++j) tm = fmaxf(tm, sv[f][j]);
    tm = fmaxf(tm, __shfl_xor(tm, 16, 64));
    tm = fmaxf(tm, __shfl_xor(tm, 32, 64));
    float m_new = fmaxf(m_run, tm);
    float alpha = (m_run == -INFINITY) ? 0.f : exp2f((m_run - m_new) * LOG2E);
    float mc    = (m_new == -INFINITY) ? 0.f : m_new * LOG2E;
    float ps = 0.f;
#pragma unroll
    for (int f = 0; f < 4; ++f) {
      float p0 = exp2f(sv[f][0] * LOG2E - mc);
      float p1 = exp2f(sv[f][1] * LOG2E - mc);
      float p2 = exp2f(sv[f][2] * LOG2E - mc);
      float p3 = exp2f(sv[f][3] * LOG2E - mc);
      ps += (p0 + p1) + (p2 + p3);
      unsigned int lo32 = (unsigned int)f2bf(p0) | ((unsigned int)f2bf(p1) << 16);
      unsigned int hi32 = (unsigned int)f2bf(p2) | ((unsigned int)f2bf(p3) << 16);
      uint2 pk; pk.x = lo32; pk.y = hi32;
      *(uint2*)(&pw[lr][f * 16 + lg * 4]) = pk;   // ds_write_b64
    }
    ps += __shfl_xor(ps, 16, 64);
    ps += __shfl_xor(ps, 32, 64);
    l_run = l_run * alpha + ps;
    m_run = m_new;
#pragma unroll
    for (int j = 0; j < 4; ++j) {
      float aj = __shfl(alpha, lg * 4 + j, 64);
      o[0][j] *= aj; o[1][j] *= aj; o[2][j] *= aj; o[3][j] *= aj;
    }
    // in-wave DS ordering: drain this wave's writes, then read (no barriers)
    asm volatile("s_waitcnt lgkmcnt(0)" ::: "memory");
    __builtin_amdgcn_sched_barrier(0);
#pragma unroll
    for (int kk = 0; kk < 2; ++kk) {
      bf16x8 pf = *(const bf16x8*)(&pw[lr][kk * 32 + lg * 8]);
#pragma unroll
      for (int n = 0; n < 4; ++n) {
        bf16x8 vf = *(const bf16x8*)(vb_ + (n * 16 + lr) * SEQ + kv + kk * 32 + lg * 8);
        o[n] = __builtin_amdgcn_mfma_f32_16x16x32_bf16(pf, vf, o[n], 0, 0, 0);
      }
    }
  }

  if (lane < 16) {
    m_l[p * 32 + lane]      = m_run;
    m_l[p * 32 + 16 + lane] = l_run;
  }
#pragma unroll
  for (int j = 0; j < 4; ++j) {
    int r = lg * 4 + j;
#pragma unroll
    for (int n = 0; n < 4; ++n)
      opart[(size_t)p * 1024 + r * 64 + n * 16 + lr] = o[n][j];
  }
}

// ---------------- Kernel 3: combine variable-split partials -----------------
__global__ __launch_bounds__(256) void combine_k(const float* __restrict__ opart,
                                                 const float* __restrict__ m_l,
                                                 float* __restrict__ out) {
  const float LOG2E = 1.44269504f;
  int idx = blockIdx.x * 256 + threadIdx.x;
  int col = idx & 63;
  int row = idx >> 6;
  int b = row >> 11, t = row & 2047;
  int qt = t >> 4, r = t & 15;
  int a = qt >> 4;
  int S = a + 1;
  int pb = b * UNITS + 8 * a * S + (qt & 15) * S;   // base slot for this q-tile
  float M = -INFINITY;
  for (int s = 0; s < S; ++s) M = fmaxf(M, m_l[(pb + s) * 32 + r]);
  float l = 0.f, o = 0.f;
  for (int s = 0; s < S; ++s) {
    float ms = m_l[(pb + s) * 32 + r];
    float w  = exp2f((ms - M) * LOG2E);
    l += m_l[(pb + s) * 32 + 16 + r] * w;
    o += opart[(size_t)(pb + s) * 1024 + r * 64 + col] * w;
  }
  out[(size_t)row * HDIM + col] = o / l;
}

// ---------------- launch ----------------------------------------------------
extern "C" void kernel_launch(void* const* d_in, const int* in_sizes, int n_in,
                              void* d_out, int out_size, void* d_ws, size_t ws_size,
                              hipStream_t stream) {
  const float* x  = (const float*)d_in[0];
  const float* wq = (const float*)d_in[1];
  const float* wk = (const float*)d_in[2];
  const float* wv = (const float*)d_in[3];
  float* outp = (float*)d_out;

  const int NP = BATCH * UNITS;                         // 4608 partial slots
  float* m_l   = (float*)d_ws;                          // [NP][32]
  float* opart = m_l + (size_t)NP * 32;                 // [NP][16][64]
  unsigned short* qbuf = (unsigned short*)(opart + (size_t)NP * 1024);
  unsigned short* kbuf = qbuf + (size_t)NROW * HDIM;
  unsigned short* vbuf = kbuf + (size_t)NROW * HDIM;    // [B][64][T]
  unsigned short* wt   = vbuf + (size_t)NROW * HDIM;    // [3][64][1024]

  hipLaunchKernelGGL(wtrans_k, dim3(48), dim3(256), 0, stream, wq, wk, wv, wt);
  hipLaunchKernelGGL(qkv_proj_k, dim3(NROW / 32), dim3(512), 0, stream, x, wt, qbuf, kbuf, vbuf);
  hipLaunchKernelGGL(attn_k, dim3(NP / 4), dim3(256), 0, stream, qbuf, kbuf, vbuf, opart, m_l);
  hipLaunchKernelGGL(combine_k, dim3(NROW * HDIM / 256), dim3(256), 0, stream, opart, m_l, outp);
}

// Round 7
// 166.084 us; speedup vs baseline: 1.0185x; 1.0185x over previous
//
#include <hip/hip_runtime.h>

// Dtype contract: device buffers FP32 (reference dtypes); internal bf16 MFMA,
// fp32 accumulate. Tolerance is bf16-grade (2% of absmax).
// dur_us model: Σ(kernels) + ~65-68 us fixed harness resets (256MiB ws poison
// 41.6 us + input restore ~21 us) — only the kernel sum is controllable.

#define BATCH 8
#define SEQ   2048
#define CIN   1024
#define HDIM  64
#define NROW  (BATCH * SEQ)      // 16384
#define NQT   (NROW / 16)        // 1024 q-tiles
#define UNITS 576                // per batch: sum over qt of (qt/16+1)

typedef __attribute__((ext_vector_type(8))) short bf16x8;
typedef __attribute__((ext_vector_type(4))) short u16x4;
typedef __attribute__((ext_vector_type(4))) float f32x4;

__device__ __forceinline__ unsigned short f2bf(float f) {
  unsigned int u = __builtin_bit_cast(unsigned int, f);
  u += 0x7fffu + ((u >> 16) & 1u);          // RNE
  return (unsigned short)(u >> 16);
}
__device__ __forceinline__ float bf2f(unsigned short h) {
  return __builtin_bit_cast(float, (unsigned int)h << 16);
}
__device__ __forceinline__ u16x4 pack4(f32x4 a) {
  u16x4 r;
  r[0] = (short)f2bf(a[0]); r[1] = (short)f2bf(a[1]);
  r[2] = (short)f2bf(a[2]); r[3] = (short)f2bf(a[3]);
  return r;
}

// ---------------- Kernel 0: W [C][HD] fp32 -> Wt [HD][C] bf16 (LDS tiles) ---
__global__ __launch_bounds__(256) void wtrans_k(const float* __restrict__ wq,
                                                const float* __restrict__ wk,
                                                const float* __restrict__ wv,
                                                unsigned short* __restrict__ wt) {
  __shared__ unsigned short lds[64][65];
  const int m  = blockIdx.x >> 4;
  const int c0 = (blockIdx.x & 15) * 64;
  const float* w = (m == 0) ? wq : (m == 1) ? wk : wv;
  const int nl = threadIdx.x & 63, gr = threadIdx.x >> 6;
#pragma unroll
  for (int i = 0; i < 16; ++i) {
    int cl = gr * 16 + i;
    lds[cl][nl] = f2bf(w[(size_t)(c0 + cl) * HDIM + nl]);
  }
  __syncthreads();
#pragma unroll
  for (int i = 0; i < 16; ++i) {
    int n = gr * 16 + i;
    wt[(size_t)m * 65536 + n * CIN + c0 + nl] = lds[nl][n];
  }
}

// ---------------- Kernel 1: QKV projection, LDS-staged GEMM -----------------
// (unchanged this round)
__global__ __launch_bounds__(512) void qkv_proj_k(const float* __restrict__ x,
                                                  const unsigned short* __restrict__ wt,
                                                  unsigned short* __restrict__ q,
                                                  unsigned short* __restrict__ k,
                                                  unsigned short* __restrict__ vt) {
  __shared__ __align__(16) unsigned char ldsb[28672];   // x @0, wt @4096
  const int tid  = threadIdx.x;
  const int lane = tid & 63;
  const int w    = tid >> 6;
  const int lr   = lane & 15, lg = lane >> 4;
  const int wm   = w & 1, wn = w >> 1;
  const int row0 = blockIdx.x * 32;

  const int trow  = tid >> 4;
  const int tcol4 = (tid & 15) * 4;
  const float* xg = x + (size_t)(row0 + trow) * CIN + tcol4;
  const int xoff  = trow * 128 + (((tcol4 >> 3) ^ (trow & 7)) << 4) + ((tcol4 & 4) << 1);

  const int wrow_ = tid >> 3;
  const int wg8   = tid & 7;
  const unsigned short* wg[3];
  int woff[3];
#pragma unroll
  for (int c = 0; c < 3; ++c) {
    int wrow = c * 64 + wrow_;
    wg[c]   = wt + (size_t)wrow * CIN + wg8 * 8;
    woff[c] = 4096 + wrow * 128 + ((wg8 ^ (wrow & 7)) << 4);
  }

  f32x4 acc[3];
#pragma unroll
  for (int i = 0; i < 3; ++i) acc[i] = (f32x4){0.f, 0.f, 0.f, 0.f};

  const int arow_off = (wm * 16 + lr) * 128;
  const int brow0    = wn * 48 + lr;

#pragma unroll 1
  for (int t = 0; t < 16; ++t) {
    const int k0 = t * 64;
    f32x4 xv = *(const f32x4*)(xg + k0);
    bf16x8 w0 = *(const bf16x8*)(wg[0] + k0);
    bf16x8 w1 = *(const bf16x8*)(wg[1] + k0);
    bf16x8 w2 = *(const bf16x8*)(wg[2] + k0);
    __syncthreads();
    *(u16x4*)(void*)(ldsb + xoff)    = pack4(xv);
    *(bf16x8*)(void*)(ldsb + woff[0]) = w0;
    *(bf16x8*)(void*)(ldsb + woff[1]) = w1;
    *(bf16x8*)(void*)(ldsb + woff[2]) = w2;
    __syncthreads();
#pragma unroll
    for (int kk = 0; kk < 2; ++kk) {
      const int swz = (((kk << 2) | lg) ^ (lr & 7)) << 4;
      bf16x8 af = *(const bf16x8*)(void*)(ldsb + arow_off + swz);
#pragma unroll
      for (int f = 0; f < 3; ++f) {
        bf16x8 bf_ = *(const bf16x8*)(void*)(ldsb + 4096 + (brow0 + f * 16) * 128 + swz);
        acc[f] = __builtin_amdgcn_mfma_f32_16x16x32_bf16(af, bf_, acc[f], 0, 0, 0);
      }
    }
  }

#pragma unroll
  for (int f = 0; f < 3; ++f) {
    const int gc  = wn * 48 + f * 16;
    const int mat = gc >> 6;
    const int hd  = (gc & 63) + lr;
#pragma unroll
    for (int j = 0; j < 4; ++j) {
      int grow = row0 + wm * 16 + lg * 4 + j;
      float v = acc[f][j];
      if (mat == 0) {
        q[(size_t)grow * HDIM + hd] = f2bf(v * 0.03125f);   // fold 1/sqrt(C)
      } else if (mat == 1) {
        k[(size_t)grow * HDIM + hd] = f2bf(v);
      } else {
        int b = grow >> 11, tp = grow & 2047;
        vt[((size_t)b * HDIM + hd) * SEQ + tp] = f2bf(v);
      }
    }
  }
}

// ---------------- Kernel 2: causal flash attention, balanced split-KV -------
// R6 lesson: without launch_bounds the compiler squeezed this into 64 VGPRs
// and serialized every VMEM op (16 x ~750cy exposed latency per tile).
// __launch_bounds__(256,3) caps at ~168 VGPR (3 waves/SIMD = 24/CU >= the
// 18 waves/CU of available work) so K+V fragments stay in flight; V is
// issued right after QK^T so its latency hides under the softmax chain.
__global__ __launch_bounds__(256, 3) void attn_k(const unsigned short* __restrict__ q,
                                                 const unsigned short* __restrict__ k,
                                                 const unsigned short* __restrict__ vt,
                                                 float* __restrict__ opart,
                                                 float* __restrict__ m_l) {
  __shared__ __align__(16) unsigned short plds[4][16][72];  // 144B row stride
  const int lane = threadIdx.x & 63;
  const int w    = threadIdx.x >> 6;
  const int lr = lane & 15, lg = lane >> 4;
  const int u    = blockIdx.x * 4 + w;      // 0 .. 8*UNITS-1
  const int b    = u / UNITS;
  const int unit = u - b * UNITS;
  // decode unit -> (a, qt, seg): band a covers units [8a(a+1), 8(a+1)(a+2))
  int a = 0;
#pragma unroll
  for (int i = 0; i < 7; ++i) if (8 * (a + 1) * (a + 2) <= unit) ++a;
  const int S    = a + 1;
  const int rem  = unit - 8 * a * S;
  const int qt   = 16 * a + rem / S;
  const int seg  = rem - (rem / S) * S;
  const int row0 = qt * 16;
  const int p    = b * UNITS + unit;        // partial slot
  unsigned short (*pw)[72] = plds[w];

  const unsigned short* qb_ = q  + (size_t)b * SEQ * HDIM;
  const unsigned short* kb_ = k  + (size_t)b * SEQ * HDIM;
  const unsigned short* vb_ = vt + (size_t)b * HDIM * SEQ;

  bf16x8 qf0 = *(const bf16x8*)(qb_ + (row0 + lr) * HDIM + lg * 8);
  bf16x8 qf1 = *(const bf16x8*)(qb_ + (row0 + lr) * HDIM + 32 + lg * 8);

  f32x4 o[4];
#pragma unroll
  for (int n = 0; n < 4; ++n) o[n] = (f32x4){0.f, 0.f, 0.f, 0.f};
  float m_run = -INFINITY, l_run = 0.f;
  const int   qrow = row0 + lr;
  const float LOG2E = 1.44269504f;
  const int nt = (qt >> 2) + 1;             // = ceil((row0+16)/64)
  const int lo = (nt * seg) / S;
  const int hi = (nt * (seg + 1)) / S;

  for (int t = lo; t < hi; ++t) {
    const int kv = t * 64;
    f32x4 sv[4];
#pragma unroll
    for (int f = 0; f < 4; ++f) {
      bf16x8 ka0 = *(const bf16x8*)(kb_ + (kv + f * 16 + lr) * HDIM + lg * 8);
      bf16x8 ka1 = *(const bf16x8*)(kb_ + (kv + f * 16 + lr) * HDIM + 32 + lg * 8);
      sv[f] = (f32x4){0.f, 0.f, 0.f, 0.f};
      sv[f] = __builtin_amdgcn_mfma_f32_16x16x32_bf16(ka0, qf0, sv[f], 0, 0, 0);
      sv[f] = __builtin_amdgcn_mfma_f32_16x16x32_bf16(ka1, qf1, sv[f], 0, 0, 0);
    }
    // issue V now: 8 VMEM in flight across the whole softmax chain
    bf16x8 vf[8];
#pragma unroll
    for (int kk = 0; kk < 2; ++kk)
#pragma unroll
      for (int n = 0; n < 4; ++n)
        vf[kk * 4 + n] = *(const bf16x8*)(vb_ + (n * 16 + lr) * SEQ + kv + kk * 32 + lg * 8);

    if (kv + 63 > row0) {                    // wave-uniform: tile touches diagonal
#pragma unroll
      for (int f = 0; f < 4; ++f)
#pragma unroll
        for (int j = 0; j < 4; ++j)
          if (kv + f * 16 + lg * 4 + j > qrow) sv[f][j] = -INFINITY;
    }
    float tm = -INFINITY;
#pragma unroll
    for (int f = 0; f < 4; ++f)
#pragma unroll
      for (int j = 0; j < 4; ++j) tm = fmaxf(tm, sv[f][j]);
    tm = fmaxf(tm, __shfl_xor(tm, 16, 64));
    tm = fmaxf(tm, __shfl_xor(tm, 32, 64));
    float m_new = fmaxf(m_run, tm);
    float alpha = (m_run == -INFINITY) ? 0.f : exp2f((m_run - m_new) * LOG2E);
    float mc    = (m_new == -INFINITY) ? 0.f : m_new * LOG2E;
    float ps = 0.f;
#pragma unroll
    for (int f = 0; f < 4; ++f) {
      float p0 = exp2f(sv[f][0] * LOG2E - mc);
      float p1 = exp2f(sv[f][1] * LOG2E - mc);
      float p2 = exp2f(sv[f][2] * LOG2E - mc);
      float p3 = exp2f(sv[f][3] * LOG2E - mc);
      ps += (p0 + p1) + (p2 + p3);
      unsigned int lo32 = (unsigned int)f2bf(p0) | ((unsigned int)f2bf(p1) << 16);
      unsigned int hi32 = (unsigned int)f2bf(p2) | ((unsigned int)f2bf(p3) << 16);
      uint2 pk; pk.x = lo32; pk.y = hi32;
      *(uint2*)(&pw[lr][f * 16 + lg * 4]) = pk;   // ds_write_b64
    }
    ps += __shfl_xor(ps, 16, 64);
    ps += __shfl_xor(ps, 32, 64);
    l_run = l_run * alpha + ps;
    m_run = m_new;
#pragma unroll
    for (int j = 0; j < 4; ++j) {
      float aj = __shfl(alpha, lg * 4 + j, 64);
      o[0][j] *= aj; o[1][j] *= aj; o[2][j] *= aj; o[3][j] *= aj;
    }
    // in-wave DS ordering: drain this wave's DS writes, then read P (no barriers)
    asm volatile("s_waitcnt lgkmcnt(0)" ::: "memory");
    __builtin_amdgcn_sched_barrier(0);
#pragma unroll
    for (int kk = 0; kk < 2; ++kk) {
      bf16x8 pf = *(const bf16x8*)(&pw[lr][kk * 32 + lg * 8]);
#pragma unroll
      for (int n = 0; n < 4; ++n)
        o[n] = __builtin_amdgcn_mfma_f32_16x16x32_bf16(pf, vf[kk * 4 + n], o[n], 0, 0, 0);
    }
  }

  if (lane < 16) {
    m_l[p * 32 + lane]      = m_run;
    m_l[p * 32 + 16 + lane] = l_run;
  }
#pragma unroll
  for (int j = 0; j < 4; ++j) {
    int r = lg * 4 + j;
#pragma unroll
    for (int n = 0; n < 4; ++n)
      opart[(size_t)p * 1024 + r * 64 + n * 16 + lr] = o[n][j];
  }
}

// ---------------- Kernel 3: combine variable-split partials -----------------
__global__ __launch_bounds__(256) void combine_k(const float* __restrict__ opart,
                                                 const float* __restrict__ m_l,
                                                 float* __restrict__ out) {
  const float LOG2E = 1.44269504f;
  int idx = blockIdx.x * 256 + threadIdx.x;
  int col = idx & 63;
  int row = idx >> 6;
  int b = row >> 11, t = row & 2047;
  int qt = t >> 4, r = t & 15;
  int a = qt >> 4;
  int S = a + 1;
  int pb = b * UNITS + 8 * a * S + (qt & 15) * S;   // base slot for this q-tile
  float M = -INFINITY;
  for (int s = 0; s < S; ++s) M = fmaxf(M, m_l[(pb + s) * 32 + r]);
  float l = 0.f, o = 0.f;
  for (int s = 0; s < S; ++s) {
    float ms = m_l[(pb + s) * 32 + r];
    float w  = exp2f((ms - M) * LOG2E);
    l += m_l[(pb + s) * 32 + 16 + r] * w;
    o += opart[(size_t)(pb + s) * 1024 + r * 64 + col] * w;
  }
  out[(size_t)row * HDIM + col] = o / l;
}

// ---------------- launch ----------------------------------------------------
extern "C" void kernel_launch(void* const* d_in, const int* in_sizes, int n_in,
                              void* d_out, int out_size, void* d_ws, size_t ws_size,
                              hipStream_t stream) {
  const float* x  = (const float*)d_in[0];
  const float* wq = (const float*)d_in[1];
  const float* wk = (const float*)d_in[2];
  const float* wv = (const float*)d_in[3];
  float* outp = (float*)d_out;

  const int NP = BATCH * UNITS;                         // 4608 partial slots
  float* m_l   = (float*)d_ws;                          // [NP][32]
  float* opart = m_l + (size_t)NP * 32;                 // [NP][16][64]
  unsigned short* qbuf = (unsigned short*)(opart + (size_t)NP * 1024);
  unsigned short* kbuf = qbuf + (size_t)NROW * HDIM;
  unsigned short* vbuf = kbuf + (size_t)NROW * HDIM;    // [B][64][T]
  unsigned short* wt   = vbuf + (size_t)NROW * HDIM;    // [3][64][1024]

  hipLaunchKernelGGL(wtrans_k, dim3(48), dim3(256), 0, stream, wq, wk, wv, wt);
  hipLaunchKernelGGL(qkv_proj_k, dim3(NROW / 32), dim3(512), 0, stream, x, wt, qbuf, kbuf, vbuf);
  hipLaunchKernelGGL(attn_k, dim3(NP / 4), dim3(256), 0, stream, qbuf, kbuf, vbuf, opart, m_l);
  hipLaunchKernelGGL(combine_k, dim3(NROW * HDIM / 256), dim3(256), 0, stream, opart, m_l, outp);
}